// Round 4
// baseline (197.862 us; speedup 1.0000x reference)
//
#include <hip/hip_runtime.h>

#define NRAYS 262144
#define KF 4
#define DF 24
#define NVERT 420000

typedef float  f32x4 __attribute__((ext_vector_type(4)));
typedef int    i32x4 __attribute__((ext_vector_type(4)));
typedef unsigned int u32x4 __attribute__((ext_vector_type(4)));

// packed bf16 vertex record: 30 bf16 values + 2 pad = 64B = one cache line
// u16[0..23] = feat, u16[24..26] = pos, u16[27..29] = nrm

__device__ __forceinline__ unsigned int f2bf(float f) {
    union { float f; unsigned int i; } c; c.f = f;
    unsigned int i = c.i;
    return (i + 0x7fffu + ((i >> 16) & 1u)) >> 16;   // round-to-nearest-even
}

__device__ __forceinline__ float bf2f(unsigned int u16) {
    union { unsigned int i; float f; } c; c.i = u16 << 16; return c.f;
}

__global__ __launch_bounds__(256) void pack_verts_bf16(
    const float* __restrict__ verts,   // [V,3]
    const float* __restrict__ vfeat,   // [V,24]
    const float* __restrict__ vnorm,   // [V,3]
    u32x4* __restrict__ pk)            // [V*4] (64B per vertex)
{
    int v = blockIdx.x * blockDim.x + threadIdx.x;
    if (v >= NVERT) return;

    float vals[30];
    const f32x4* fr = reinterpret_cast<const f32x4*>(vfeat + (size_t)v * DF);
#pragma unroll
    for (int q = 0; q < 6; ++q) {
        f32x4 a = __builtin_nontemporal_load(fr + q);
        vals[q * 4 + 0] = a.x; vals[q * 4 + 1] = a.y;
        vals[q * 4 + 2] = a.z; vals[q * 4 + 3] = a.w;
    }
#pragma unroll
    for (int j = 0; j < 3; ++j) {
        vals[24 + j] = __builtin_nontemporal_load(verts + (size_t)v * 3 + j);
        vals[27 + j] = __builtin_nontemporal_load(vnorm + (size_t)v * 3 + j);
    }

    unsigned int rec[16];
#pragma unroll
    for (int j = 0; j < 15; ++j) {
        rec[j] = f2bf(vals[2 * j]) | (f2bf(vals[2 * j + 1]) << 16);
    }
    rec[15] = 0;

    u32x4* out = pk + (size_t)v * 4;
#pragma unroll
    for (int q = 0; q < 4; ++q) {
        u32x4 o;
        o.x = rec[q * 4 + 0]; o.y = rec[q * 4 + 1];
        o.z = rec[q * 4 + 2]; o.w = rec[q * 4 + 3];
        out[q] = o;   // normal (cached) store — we WANT the table resident
    }
}

template<bool PACKED>
__global__ __launch_bounds__(256) void dnmp_rk(
    const float* __restrict__ bary_coords,  // [P,4,3]
    const float* __restrict__ zbuf,         // [P,4]
    const float* __restrict__ verts,        // [V,3]
    const float* __restrict__ vfeat,        // [V,24]
    const float* __restrict__ vnorm,        // [V,3]
    const int*   __restrict__ p2f_all,      // [P,4]
    const int*   __restrict__ faces,        // [F,3]
    const int*   __restrict__ pix,          // [R]
    const u32x4* __restrict__ pk,           // [V*4] packed bf16 (or null)
    float* __restrict__ out_tex,            // [R,4,24]
    float* __restrict__ out_pts,            // [R,4,3]
    float* __restrict__ out_dep,            // [R,4]
    float* __restrict__ out_nrm)            // [R,4,3]
{
    int tid = blockIdx.x * blockDim.x + threadIdx.x;
    int r = tid >> 2;
    if (r >= NRAYS) return;
    int k = tid & 3;
    int lane = threadIdx.x & 63;
    int gbase = lane & ~3;   // base lane of this ray's 4-lane group

    int p = __builtin_nontemporal_load(pix + r);
    int   f = __builtin_nontemporal_load(p2f_all + (size_t)p * 4 + k);
    float d = __builtin_nontemporal_load(zbuf + (size_t)p * 4 + k);
    const float* bb = bary_coords + (size_t)p * 12 + k * 3;
    float w0 = __builtin_nontemporal_load(bb + 0);
    float w1 = __builtin_nontemporal_load(bb + 1);
    float w2 = __builtin_nontemporal_load(bb + 2);

    // fallback: invalid (== -1) entries take k=0's face/bary/depth
    int   f0  = __shfl(f,  gbase, 64);
    float dd0 = __shfl(d,  gbase, 64);
    float w00 = __shfl(w0, gbase, 64);
    float w01 = __shfl(w1, gbase, 64);
    float w02 = __shfl(w2, gbase, 64);
    if (f == -1) { f = f0; d = dd0; w0 = w00; w1 = w01; w2 = w02; }

    // stable argsort rank over post-fallback depths (cross-lane within group)
    int rank = 0;
#pragma unroll
    for (int j = 0; j < 4; ++j) {
        float dj = __shfl(d, gbase + j, 64);
        rank += (dj < d || (dj == d && j < k)) ? 1 : 0;
    }

    bool mask = f < 0;
    int  idx  = mask ? 0 : f;
    if (mask) { w0 = 0.f; w1 = 0.f; w2 = 0.f; }

    // faces: cached load (small hot table, keep resident)
    int i0 = faces[(size_t)idx * 3 + 0];
    int i1 = faces[(size_t)idx * 3 + 1];
    int i2 = faces[(size_t)idx * 3 + 2];

    float acc[30];
#pragma unroll
    for (int i = 0; i < 30; ++i) acc[i] = 0.f;

    const int   vi[3] = { i0, i1, i2 };
    const float ww[3] = { w0, w1, w2 };

#pragma unroll
    for (int t = 0; t < 3; ++t) {
        float w = ww[t];
        if (PACKED) {
            const u32x4* row = pk + (size_t)vi[t] * 4;  // cached: hot table
            unsigned int rec[16];
#pragma unroll
            for (int q = 0; q < 4; ++q) {
                u32x4 a = row[q];
                rec[q * 4 + 0] = a.x; rec[q * 4 + 1] = a.y;
                rec[q * 4 + 2] = a.z; rec[q * 4 + 3] = a.w;
            }
#pragma unroll
            for (int e = 0; e < 30; ++e) {
                unsigned int word = rec[e >> 1];
                unsigned int u = (e & 1) ? (word >> 16) : (word & 0xffffu);
                acc[e] += w * bf2f(u);
            }
        } else {
            const float4* trow = reinterpret_cast<const float4*>(vfeat + (size_t)vi[t] * DF);
#pragma unroll
            for (int q = 0; q < 6; ++q) {
                float4 a = trow[q];
                acc[q * 4 + 0] += w * a.x;
                acc[q * 4 + 1] += w * a.y;
                acc[q * 4 + 2] += w * a.z;
                acc[q * 4 + 3] += w * a.w;
            }
            const float* vv = verts + (size_t)vi[t] * 3;
            const float* nn = vnorm + (size_t)vi[t] * 3;
            acc[24] += w * vv[0]; acc[25] += w * vv[1]; acc[26] += w * vv[2];
            acc[27] += w * nn[0]; acc[28] += w * nn[1]; acc[29] += w * nn[2];
        }
    }

    int ob = r * KF + rank;
    f32x4* ot = reinterpret_cast<f32x4*>(out_tex) + (size_t)ob * 6;
#pragma unroll
    for (int q = 0; q < 6; ++q) {
        f32x4 o;
        o.x = acc[q * 4 + 0]; o.y = acc[q * 4 + 1];
        o.z = acc[q * 4 + 2]; o.w = acc[q * 4 + 3];
        __builtin_nontemporal_store(o, ot + q);
    }
#pragma unroll
    for (int j = 0; j < 3; ++j) {
        __builtin_nontemporal_store(acc[24 + j], out_pts + (size_t)ob * 3 + j);
        __builtin_nontemporal_store(acc[27 + j], out_nrm + (size_t)ob * 3 + j);
    }
    __builtin_nontemporal_store(d, out_dep + ob);
}

extern "C" void kernel_launch(void* const* d_in, const int* in_sizes, int n_in,
                              void* d_out, int out_size, void* d_ws, size_t ws_size,
                              hipStream_t stream) {
    const float* bary_coords = (const float*)d_in[0];  // [P,4,3]
    const float* zbuf        = (const float*)d_in[1];  // [P,4]
    const float* verts       = (const float*)d_in[2];  // [V,3]
    const float* vfeat       = (const float*)d_in[3];  // [V,24]
    const float* vnorm       = (const float*)d_in[4];  // [V,3]
    const int*   p2f         = (const int*)d_in[5];    // [P,4]
    const int*   faces       = (const int*)d_in[6];    // [F,3]
    const int*   pix         = (const int*)d_in[7];    // [R]

    float* out     = (float*)d_out;
    float* out_tex = out;                                   // R*4*24
    float* out_pts = out_tex + (size_t)NRAYS * KF * DF;     // R*4*3
    float* out_dep = out_pts + (size_t)NRAYS * KF * 3;      // R*4
    float* out_nrm = out_dep + (size_t)NRAYS * KF;          // R*4*3

    const size_t pk_bytes = (size_t)NVERT * 4 * sizeof(u32x4);  // 26.9 MB

    dim3 block(256);
    dim3 grid_main(((size_t)NRAYS * KF + 255) / 256);

    if (ws_size >= pk_bytes) {
        u32x4* pk = (u32x4*)d_ws;
        dim3 grid_pack((NVERT + 255) / 256);
        pack_verts_bf16<<<grid_pack, block, 0, stream>>>(verts, vfeat, vnorm, pk);
        dnmp_rk<true><<<grid_main, block, 0, stream>>>(
            bary_coords, zbuf, verts, vfeat, vnorm, p2f, faces, pix, pk,
            out_tex, out_pts, out_dep, out_nrm);
    } else {
        dnmp_rk<false><<<grid_main, block, 0, stream>>>(
            bary_coords, zbuf, verts, vfeat, vnorm, p2f, faces, pix, nullptr,
            out_tex, out_pts, out_dep, out_nrm);
    }
}

// Round 5
// 136.761 us; speedup vs baseline: 1.4468x; 1.4468x over previous
//
#include <hip/hip_runtime.h>

#define NRAYS 262144
#define KF 4
#define DF 24
#define NVERT 420000

typedef float        f32x4 __attribute__((ext_vector_type(4)));
typedef unsigned int u32x4 __attribute__((ext_vector_type(4)));

// packed bf16 vertex record: 30 bf16 values + 2 pad = 64B = one cache line
// u16[0..23] = feat, u16[24..26] = pos, u16[27..29] = nrm

__device__ __forceinline__ unsigned int f2bf(float f) {
    union { float f; unsigned int i; } c; c.f = f;
    unsigned int i = c.i;
    return (i + 0x7fffu + ((i >> 16) & 1u)) >> 16;   // round-to-nearest-even
}

__device__ __forceinline__ float bfl(unsigned int w) {
    union { unsigned int i; float f; } c; c.i = w << 16; return c.f;
}
__device__ __forceinline__ float bfh(unsigned int w) {
    union { unsigned int i; float f; } c; c.i = w & 0xffff0000u; return c.f;
}

__global__ __launch_bounds__(256) void pack_verts_bf16(
    const float* __restrict__ verts,   // [V,3]
    const float* __restrict__ vfeat,   // [V,24]
    const float* __restrict__ vnorm,   // [V,3]
    u32x4* __restrict__ pk)            // [V*4] (64B per vertex)
{
    int v = blockIdx.x * blockDim.x + threadIdx.x;
    if (v >= NVERT) return;

    float vals[30];
    const f32x4* fr = reinterpret_cast<const f32x4*>(vfeat + (size_t)v * DF);
#pragma unroll
    for (int q = 0; q < 6; ++q) {
        f32x4 a = fr[q];
        vals[q * 4 + 0] = a.x; vals[q * 4 + 1] = a.y;
        vals[q * 4 + 2] = a.z; vals[q * 4 + 3] = a.w;
    }
#pragma unroll
    for (int j = 0; j < 3; ++j) {
        vals[24 + j] = verts[(size_t)v * 3 + j];
        vals[27 + j] = vnorm[(size_t)v * 3 + j];
    }

    unsigned int rec[16];
#pragma unroll
    for (int j = 0; j < 15; ++j) {
        rec[j] = f2bf(vals[2 * j]) | (f2bf(vals[2 * j + 1]) << 16);
    }
    rec[15] = 0;

    u32x4* out = pk + (size_t)v * 4;
#pragma unroll
    for (int q = 0; q < 4; ++q) {
        u32x4 o;
        o.x = rec[q * 4 + 0]; o.y = rec[q * 4 + 1];
        o.z = rec[q * 4 + 2]; o.w = rec[q * 4 + 3];
        out[q] = o;
    }
}

template<bool PACKED>
__global__ __launch_bounds__(256) void dnmp_rk(
    const float* __restrict__ bary_coords,  // [P,4,3]
    const float* __restrict__ zbuf,         // [P,4]
    const float* __restrict__ verts,        // [V,3]
    const float* __restrict__ vfeat,        // [V,24]
    const float* __restrict__ vnorm,        // [V,3]
    const int*   __restrict__ p2f_all,      // [P,4]
    const int*   __restrict__ faces,        // [F,3]
    const int*   __restrict__ pix,          // [R]
    const u32x4* __restrict__ pk,           // [V*4] packed bf16 (or null)
    float* __restrict__ out_tex,            // [R,4,24]
    float* __restrict__ out_pts,            // [R,4,3]
    float* __restrict__ out_dep,            // [R,4]
    float* __restrict__ out_nrm)            // [R,4,3]
{
    int tid = blockIdx.x * blockDim.x + threadIdx.x;
    int r = tid >> 2;
    if (r >= NRAYS) return;
    int k = tid & 3;
    int lane = threadIdx.x & 63;
    int gbase = lane & ~3;   // base lane of this ray's 4-lane group

    int p = pix[r];
    int   f = p2f_all[(size_t)p * 4 + k];
    float d = zbuf[(size_t)p * 4 + k];
    const float* bb = bary_coords + (size_t)p * 12 + k * 3;
    float w0 = bb[0], w1 = bb[1], w2 = bb[2];

    // fallback: invalid (== -1) entries take k=0's face/bary/depth
    int   f0  = __shfl(f,  gbase, 64);
    float dd0 = __shfl(d,  gbase, 64);
    float w00 = __shfl(w0, gbase, 64);
    float w01 = __shfl(w1, gbase, 64);
    float w02 = __shfl(w2, gbase, 64);
    if (f == -1) { f = f0; d = dd0; w0 = w00; w1 = w01; w2 = w02; }

    // stable argsort rank over post-fallback depths (cross-lane within group)
    int rank = 0;
#pragma unroll
    for (int j = 0; j < 4; ++j) {
        float dj = __shfl(d, gbase + j, 64);
        rank += (dj < d || (dj == d && j < k)) ? 1 : 0;
    }

    bool mask = f < 0;
    int  idx  = mask ? 0 : f;
    if (mask) { w0 = 0.f; w1 = 0.f; w2 = 0.f; }

    int i0 = faces[(size_t)idx * 3 + 0];
    int i1 = faces[(size_t)idx * 3 + 1];
    int i2 = faces[(size_t)idx * 3 + 2];

    int ob = r * KF + rank;

    if (PACKED) {
        // Batch ALL 12 record loads into registers before any arithmetic:
        // maximizes outstanding L2-miss requests per wave (MLP).
        const u32x4* ra = pk + (size_t)i0 * 4;
        const u32x4* rb = pk + (size_t)i1 * 4;
        const u32x4* rc = pk + (size_t)i2 * 4;
        u32x4 qa0 = ra[0], qa1 = ra[1], qa2 = ra[2], qa3 = ra[3];
        u32x4 qb0 = rb[0], qb1 = rb[1], qb2 = rb[2], qb3 = rb[3];
        u32x4 qc0 = rc[0], qc1 = rc[1], qc2 = rc[2], qc3 = rc[3];

        unsigned int a[16] = { qa0.x, qa0.y, qa0.z, qa0.w,
                               qa1.x, qa1.y, qa1.z, qa1.w,
                               qa2.x, qa2.y, qa2.z, qa2.w,
                               qa3.x, qa3.y, qa3.z, qa3.w };
        unsigned int b[16] = { qb0.x, qb0.y, qb0.z, qb0.w,
                               qb1.x, qb1.y, qb1.z, qb1.w,
                               qb2.x, qb2.y, qb2.z, qb2.w,
                               qb3.x, qb3.y, qb3.z, qb3.w };
        unsigned int c[16] = { qc0.x, qc0.y, qc0.z, qc0.w,
                               qc1.x, qc1.y, qc1.z, qc1.w,
                               qc2.x, qc2.y, qc2.z, qc2.w,
                               qc3.x, qc3.y, qc3.z, qc3.w };

        float o[30];
#pragma unroll
        for (int j = 0; j < 15; ++j) {
            o[2 * j + 0] = w0 * bfl(a[j]) + w1 * bfl(b[j]) + w2 * bfl(c[j]);
            o[2 * j + 1] = w0 * bfh(a[j]) + w1 * bfh(b[j]) + w2 * bfh(c[j]);
        }

        f32x4* ot = reinterpret_cast<f32x4*>(out_tex) + (size_t)ob * 6;
#pragma unroll
        for (int q = 0; q < 6; ++q) {
            f32x4 v;
            v.x = o[q * 4 + 0]; v.y = o[q * 4 + 1];
            v.z = o[q * 4 + 2]; v.w = o[q * 4 + 3];
            ot[q] = v;
        }
#pragma unroll
        for (int j = 0; j < 3; ++j) {
            out_pts[(size_t)ob * 3 + j] = o[24 + j];
            out_nrm[(size_t)ob * 3 + j] = o[27 + j];
        }
    } else {
        float acc[30];
#pragma unroll
        for (int i = 0; i < 30; ++i) acc[i] = 0.f;
        const int   vi[3] = { i0, i1, i2 };
        const float ww[3] = { w0, w1, w2 };
#pragma unroll
        for (int t = 0; t < 3; ++t) {
            float w = ww[t];
            const float4* trow = reinterpret_cast<const float4*>(vfeat + (size_t)vi[t] * DF);
#pragma unroll
            for (int q = 0; q < 6; ++q) {
                float4 a = trow[q];
                acc[q * 4 + 0] += w * a.x;
                acc[q * 4 + 1] += w * a.y;
                acc[q * 4 + 2] += w * a.z;
                acc[q * 4 + 3] += w * a.w;
            }
            const float* vv = verts + (size_t)vi[t] * 3;
            const float* nn = vnorm + (size_t)vi[t] * 3;
            acc[24] += w * vv[0]; acc[25] += w * vv[1]; acc[26] += w * vv[2];
            acc[27] += w * nn[0]; acc[28] += w * nn[1]; acc[29] += w * nn[2];
        }
        float4* ot = reinterpret_cast<float4*>(out_tex) + (size_t)ob * 6;
#pragma unroll
        for (int q = 0; q < 6; ++q) {
            ot[q] = make_float4(acc[q * 4 + 0], acc[q * 4 + 1], acc[q * 4 + 2], acc[q * 4 + 3]);
        }
#pragma unroll
        for (int j = 0; j < 3; ++j) {
            out_pts[(size_t)ob * 3 + j] = acc[24 + j];
            out_nrm[(size_t)ob * 3 + j] = acc[27 + j];
        }
    }

    out_dep[ob] = d;
}

extern "C" void kernel_launch(void* const* d_in, const int* in_sizes, int n_in,
                              void* d_out, int out_size, void* d_ws, size_t ws_size,
                              hipStream_t stream) {
    const float* bary_coords = (const float*)d_in[0];  // [P,4,3]
    const float* zbuf        = (const float*)d_in[1];  // [P,4]
    const float* verts       = (const float*)d_in[2];  // [V,3]
    const float* vfeat       = (const float*)d_in[3];  // [V,24]
    const float* vnorm       = (const float*)d_in[4];  // [V,3]
    const int*   p2f         = (const int*)d_in[5];    // [P,4]
    const int*   faces       = (const int*)d_in[6];    // [F,3]
    const int*   pix         = (const int*)d_in[7];    // [R]

    float* out     = (float*)d_out;
    float* out_tex = out;                                   // R*4*24
    float* out_pts = out_tex + (size_t)NRAYS * KF * DF;     // R*4*3
    float* out_dep = out_pts + (size_t)NRAYS * KF * 3;      // R*4
    float* out_nrm = out_dep + (size_t)NRAYS * KF;          // R*4*3

    const size_t pk_bytes = (size_t)NVERT * 4 * sizeof(u32x4);  // 26.9 MB

    dim3 block(256);
    dim3 grid_main(((size_t)NRAYS * KF + 255) / 256);

    if (ws_size >= pk_bytes) {
        u32x4* pk = (u32x4*)d_ws;
        dim3 grid_pack((NVERT + 255) / 256);
        pack_verts_bf16<<<grid_pack, block, 0, stream>>>(verts, vfeat, vnorm, pk);
        dnmp_rk<true><<<grid_main, block, 0, stream>>>(
            bary_coords, zbuf, verts, vfeat, vnorm, p2f, faces, pix, pk,
            out_tex, out_pts, out_dep, out_nrm);
    } else {
        dnmp_rk<false><<<grid_main, block, 0, stream>>>(
            bary_coords, zbuf, verts, vfeat, vnorm, p2f, faces, pix, nullptr,
            out_tex, out_pts, out_dep, out_nrm);
    }
}

// Round 6
// 131.252 us; speedup vs baseline: 1.5075x; 1.0420x over previous
//
#include <hip/hip_runtime.h>

#define NRAYS 262144
#define KF 4
#define DF 24
#define NVERT 420000

typedef float        f32x4 __attribute__((ext_vector_type(4)));
typedef unsigned int u32x4 __attribute__((ext_vector_type(4)));

// packed bf16 vertex record: 30 bf16 values + 2 pad = 64B = one cache line
// u16[0..23] = feat, u16[24..26] = pos, u16[27..29] = nrm

__device__ __forceinline__ unsigned int f2bf(float f) {
    union { float f; unsigned int i; } c; c.f = f;
    unsigned int i = c.i;
    return (i + 0x7fffu + ((i >> 16) & 1u)) >> 16;   // round-to-nearest-even
}

__device__ __forceinline__ float bfl(unsigned int w) {
    union { unsigned int i; float f; } c; c.i = w << 16; return c.f;
}
__device__ __forceinline__ float bfh(unsigned int w) {
    union { unsigned int i; float f; } c; c.i = w & 0xffff0000u; return c.f;
}

__global__ __launch_bounds__(256) void pack_verts_bf16(
    const float* __restrict__ verts,   // [V,3]
    const float* __restrict__ vfeat,   // [V,24]
    const float* __restrict__ vnorm,   // [V,3]
    u32x4* __restrict__ pk)            // [V*4] (64B per vertex)
{
    int v = blockIdx.x * blockDim.x + threadIdx.x;
    if (v >= NVERT) return;

    float vals[30];
    const f32x4* fr = reinterpret_cast<const f32x4*>(vfeat + (size_t)v * DF);
#pragma unroll
    for (int q = 0; q < 6; ++q) {
        f32x4 a = fr[q];
        vals[q * 4 + 0] = a.x; vals[q * 4 + 1] = a.y;
        vals[q * 4 + 2] = a.z; vals[q * 4 + 3] = a.w;
    }
#pragma unroll
    for (int j = 0; j < 3; ++j) {
        vals[24 + j] = verts[(size_t)v * 3 + j];
        vals[27 + j] = vnorm[(size_t)v * 3 + j];
    }

    unsigned int rec[16];
#pragma unroll
    for (int j = 0; j < 15; ++j) {
        rec[j] = f2bf(vals[2 * j]) | (f2bf(vals[2 * j + 1]) << 16);
    }
    rec[15] = 0;

    u32x4* out = pk + (size_t)v * 4;
#pragma unroll
    for (int q = 0; q < 4; ++q) {
        u32x4 o;
        o.x = rec[q * 4 + 0]; o.y = rec[q * 4 + 1];
        o.z = rec[q * 4 + 2]; o.w = rec[q * 4 + 3];
        out[q] = o;
    }
}

template<bool PACKED>
__global__ __launch_bounds__(256, 1) void dnmp_rk(
    const float* __restrict__ bary_coords,  // [P,4,3]
    const float* __restrict__ zbuf,         // [P,4]
    const float* __restrict__ verts,        // [V,3]
    const float* __restrict__ vfeat,        // [V,24]
    const float* __restrict__ vnorm,        // [V,3]
    const int*   __restrict__ p2f_all,      // [P,4]
    const int*   __restrict__ faces,        // [F,3]
    const int*   __restrict__ pix,          // [R]
    const u32x4* __restrict__ pk,           // [V*4] packed bf16 (or null)
    float* __restrict__ out_tex,            // [R,4,24]
    float* __restrict__ out_pts,            // [R,4,3]
    float* __restrict__ out_dep,            // [R,4]
    float* __restrict__ out_nrm)            // [R,4,3]
{
    int tid = blockIdx.x * blockDim.x + threadIdx.x;
    int r = tid >> 2;
    if (r >= NRAYS) return;
    int k = tid & 3;
    int lane = threadIdx.x & 63;
    int gbase = lane & ~3;   // base lane of this ray's 4-lane group

    int p = pix[r];
    int   f = p2f_all[(size_t)p * 4 + k];
    float d = zbuf[(size_t)p * 4 + k];
    const float* bb = bary_coords + (size_t)p * 12 + k * 3;
    float w0 = bb[0], w1 = bb[1], w2 = bb[2];

    // fallback: invalid (== -1) entries take k=0's face/bary/depth
    int   f0  = __shfl(f,  gbase, 64);
    float dd0 = __shfl(d,  gbase, 64);
    float w00 = __shfl(w0, gbase, 64);
    float w01 = __shfl(w1, gbase, 64);
    float w02 = __shfl(w2, gbase, 64);
    if (f == -1) { f = f0; d = dd0; w0 = w00; w1 = w01; w2 = w02; }

    // stable argsort rank over post-fallback depths (cross-lane within group)
    int rank = 0;
#pragma unroll
    for (int j = 0; j < 4; ++j) {
        float dj = __shfl(d, gbase + j, 64);
        rank += (dj < d || (dj == d && j < k)) ? 1 : 0;
    }

    bool mask = f < 0;
    int  idx  = mask ? 0 : f;
    if (mask) { w0 = 0.f; w1 = 0.f; w2 = 0.f; }

    int i0 = faces[(size_t)idx * 3 + 0];
    int i1 = faces[(size_t)idx * 3 + 1];
    int i2 = faces[(size_t)idx * 3 + 2];

    int ob = r * KF + rank;

    if (PACKED) {
        // Issue ALL 12 record loads before any arithmetic; the sched_barrier
        // fences the scheduler so it cannot sink loads into the FMA stream,
        // forcing 12 outstanding 64B gathers per lane (MLP test).
        const u32x4* ra = pk + (size_t)i0 * 4;
        const u32x4* rb = pk + (size_t)i1 * 4;
        const u32x4* rc = pk + (size_t)i2 * 4;
        u32x4 qa0 = ra[0], qa1 = ra[1], qa2 = ra[2], qa3 = ra[3];
        u32x4 qb0 = rb[0], qb1 = rb[1], qb2 = rb[2], qb3 = rb[3];
        u32x4 qc0 = rc[0], qc1 = rc[1], qc2 = rc[2], qc3 = rc[3];
        __builtin_amdgcn_sched_barrier(0);

        unsigned int a[16] = { qa0.x, qa0.y, qa0.z, qa0.w,
                               qa1.x, qa1.y, qa1.z, qa1.w,
                               qa2.x, qa2.y, qa2.z, qa2.w,
                               qa3.x, qa3.y, qa3.z, qa3.w };
        unsigned int b[16] = { qb0.x, qb0.y, qb0.z, qb0.w,
                               qb1.x, qb1.y, qb1.z, qb1.w,
                               qb2.x, qb2.y, qb2.z, qb2.w,
                               qb3.x, qb3.y, qb3.z, qb3.w };
        unsigned int c[16] = { qc0.x, qc0.y, qc0.z, qc0.w,
                               qc1.x, qc1.y, qc1.z, qc1.w,
                               qc2.x, qc2.y, qc2.z, qc2.w,
                               qc3.x, qc3.y, qc3.z, qc3.w };

        float o[30];
#pragma unroll
        for (int j = 0; j < 15; ++j) {
            o[2 * j + 0] = w0 * bfl(a[j]) + w1 * bfl(b[j]) + w2 * bfl(c[j]);
            o[2 * j + 1] = w0 * bfh(a[j]) + w1 * bfh(b[j]) + w2 * bfh(c[j]);
        }

        f32x4* ot = reinterpret_cast<f32x4*>(out_tex) + (size_t)ob * 6;
#pragma unroll
        for (int q = 0; q < 6; ++q) {
            f32x4 v;
            v.x = o[q * 4 + 0]; v.y = o[q * 4 + 1];
            v.z = o[q * 4 + 2]; v.w = o[q * 4 + 3];
            ot[q] = v;
        }
#pragma unroll
        for (int j = 0; j < 3; ++j) {
            out_pts[(size_t)ob * 3 + j] = o[24 + j];
            out_nrm[(size_t)ob * 3 + j] = o[27 + j];
        }
    } else {
        float acc[30];
#pragma unroll
        for (int i = 0; i < 30; ++i) acc[i] = 0.f;
        const int   vi[3] = { i0, i1, i2 };
        const float ww[3] = { w0, w1, w2 };
#pragma unroll
        for (int t = 0; t < 3; ++t) {
            float w = ww[t];
            const float4* trow = reinterpret_cast<const float4*>(vfeat + (size_t)vi[t] * DF);
#pragma unroll
            for (int q = 0; q < 6; ++q) {
                float4 a = trow[q];
                acc[q * 4 + 0] += w * a.x;
                acc[q * 4 + 1] += w * a.y;
                acc[q * 4 + 2] += w * a.z;
                acc[q * 4 + 3] += w * a.w;
            }
            const float* vv = verts + (size_t)vi[t] * 3;
            const float* nn = vnorm + (size_t)vi[t] * 3;
            acc[24] += w * vv[0]; acc[25] += w * vv[1]; acc[26] += w * vv[2];
            acc[27] += w * nn[0]; acc[28] += w * nn[1]; acc[29] += w * nn[2];
        }
        float4* ot = reinterpret_cast<float4*>(out_tex) + (size_t)ob * 6;
#pragma unroll
        for (int q = 0; q < 6; ++q) {
            ot[q] = make_float4(acc[q * 4 + 0], acc[q * 4 + 1], acc[q * 4 + 2], acc[q * 4 + 3]);
        }
#pragma unroll
        for (int j = 0; j < 3; ++j) {
            out_pts[(size_t)ob * 3 + j] = acc[24 + j];
            out_nrm[(size_t)ob * 3 + j] = acc[27 + j];
        }
    }

    out_dep[ob] = d;
}

extern "C" void kernel_launch(void* const* d_in, const int* in_sizes, int n_in,
                              void* d_out, int out_size, void* d_ws, size_t ws_size,
                              hipStream_t stream) {
    const float* bary_coords = (const float*)d_in[0];  // [P,4,3]
    const float* zbuf        = (const float*)d_in[1];  // [P,4]
    const float* verts       = (const float*)d_in[2];  // [V,3]
    const float* vfeat       = (const float*)d_in[3];  // [V,24]
    const float* vnorm       = (const float*)d_in[4];  // [V,3]
    const int*   p2f         = (const int*)d_in[5];    // [P,4]
    const int*   faces       = (const int*)d_in[6];    // [F,3]
    const int*   pix         = (const int*)d_in[7];    // [R]

    float* out     = (float*)d_out;
    float* out_tex = out;                                   // R*4*24
    float* out_pts = out_tex + (size_t)NRAYS * KF * DF;     // R*4*3
    float* out_dep = out_pts + (size_t)NRAYS * KF * 3;      // R*4
    float* out_nrm = out_dep + (size_t)NRAYS * KF;          // R*4*3

    const size_t pk_bytes = (size_t)NVERT * 4 * sizeof(u32x4);  // 26.9 MB

    dim3 block(256);
    dim3 grid_main(((size_t)NRAYS * KF + 255) / 256);

    if (ws_size >= pk_bytes) {
        u32x4* pk = (u32x4*)d_ws;
        dim3 grid_pack((NVERT + 255) / 256);
        pack_verts_bf16<<<grid_pack, block, 0, stream>>>(verts, vfeat, vnorm, pk);
        dnmp_rk<true><<<grid_main, block, 0, stream>>>(
            bary_coords, zbuf, verts, vfeat, vnorm, p2f, faces, pix, pk,
            out_tex, out_pts, out_dep, out_nrm);
    } else {
        dnmp_rk<false><<<grid_main, block, 0, stream>>>(
            bary_coords, zbuf, verts, vfeat, vnorm, p2f, faces, pix, nullptr,
            out_tex, out_pts, out_dep, out_nrm);
    }
}